// Round 3
// baseline (9558.068 us; speedup 1.0000x reference)
//
#include <hip/hip_runtime.h>
#include <hip/hip_bf16.h>
#include <math.h>

#define BB 64
#define NPIX 196
#define ENCD 2048
#define DECD 512
#define VOCAB_N 10000
#define MAXLEN 52
#define TT 51
#define NPADFC 10048
#define NBLK 256

// Output layout (floats): preds | captions | declens | alphas
#define PRED_SZ   (BB * TT * VOCAB_N)
#define CAPS_SZ   (BB * MAXLEN)
#define LENS_SZ   (BB)
#define ALPHAS_OFF (PRED_SZ + CAPS_SZ + LENS_SZ)

typedef __attribute__((ext_vector_type(8))) short short8;
typedef __attribute__((ext_vector_type(4))) float f32x4;

__device__ __forceinline__ float fsigm(float x) {
    return 1.0f / (1.0f + __expf(-x));
}
__device__ __forceinline__ float ftanh(float x) {
    x = fminf(fmaxf(x, -15.0f), 15.0f);
    float e = __expf(2.0f * x);
    return (e - 1.0f) / (e + 1.0f);
}
__device__ __forceinline__ float bf2f(unsigned short u) {
    union { unsigned int i; float f; } v;
    v.i = ((unsigned int)u) << 16;
    return v.f;
}
__device__ __forceinline__ unsigned short f2bf(float f) {
    union { float f; unsigned int i; } v;
    v.f = f;
    unsigned int r = v.i + 0x7FFFu + ((v.i >> 16) & 1u);
    return (unsigned short)(r >> 16);
}

// ---------------------------------------------------------------------------
// Device-scope grid barrier: monotonic counter, release add + relaxed spin +
// acquire fence. Requires all NBLK blocks resident (grid=256, 1+ blk/CU).
// ---------------------------------------------------------------------------
__device__ __forceinline__ void gridbar(unsigned int* cnt, unsigned int target)
{
    __syncthreads();
    if (threadIdx.x == 0) {
        __hip_atomic_fetch_add(cnt, 1u, __ATOMIC_RELEASE, __HIP_MEMORY_SCOPE_AGENT);
        while (__hip_atomic_load(cnt, __ATOMIC_RELAXED, __HIP_MEMORY_SCOPE_AGENT) < target)
            __builtin_amdgcn_s_sleep(4);
        __threadfence();
    }
    __syncthreads();
}

// ---------------------------------------------------------------------------
// MFMA GEMM tile (64 rows x 64 cols), bf16 in fp32 acc, 2-deep prefetch.
// A row-major (lda elems). Wp packed: Wp[kb][n][kk], kk=0..31. nkb EVEN.
// 4 waves: wave w rows m0+16w..+15; each wave 4 col-fragments n0..n0+63.
// ---------------------------------------------------------------------------
__device__ __forceinline__ void gemm_tile(
    const unsigned short* __restrict__ A, int lda,
    const unsigned short* __restrict__ Wp, int Npad, int nkb,
    float* __restrict__ C, unsigned short* __restrict__ C16, long ldc,
    const float* __restrict__ bias, int N, int act,
    const int* __restrict__ caplen, int t, int n0, int m0)
{
    const int w  = threadIdx.x >> 6;
    const int l  = threadIdx.x & 63;
    const int lr = l & 15;
    const int q  = l >> 4;

    const unsigned short* ap = A + (size_t)(m0 + 16 * w + lr) * lda + q * 8;
    const unsigned short* bp = Wp + (size_t)(n0 + lr) * 32 + q * 8;
    const size_t bstep = (size_t)Npad * 32;

    f32x4 acc[4];
#pragma unroll
    for (int i = 0; i < 4; ++i) acc[i] = (f32x4){0.f, 0.f, 0.f, 0.f};

    short8 aE  = *(const short8*)ap;
    short8 bE0 = *(const short8*)(bp);
    short8 bE1 = *(const short8*)(bp + 512);
    short8 bE2 = *(const short8*)(bp + 1024);
    short8 bE3 = *(const short8*)(bp + 1536);
    short8 aO  = *(const short8*)(ap + 32);
    short8 bO0 = *(const short8*)(bp + bstep);
    short8 bO1 = *(const short8*)(bp + bstep + 512);
    short8 bO2 = *(const short8*)(bp + bstep + 1024);
    short8 bO3 = *(const short8*)(bp + bstep + 1536);

    for (int kb = 0; kb < nkb; kb += 2) {
        acc[0] = __builtin_amdgcn_mfma_f32_16x16x32_bf16(aE, bE0, acc[0], 0, 0, 0);
        acc[1] = __builtin_amdgcn_mfma_f32_16x16x32_bf16(aE, bE1, acc[1], 0, 0, 0);
        acc[2] = __builtin_amdgcn_mfma_f32_16x16x32_bf16(aE, bE2, acc[2], 0, 0, 0);
        acc[3] = __builtin_amdgcn_mfma_f32_16x16x32_bf16(aE, bE3, acc[3], 0, 0, 0);
        if (kb + 2 < nkb) {
            const unsigned short* a2 = ap + (size_t)(kb + 2) * 32;
            const unsigned short* b2 = bp + (size_t)(kb + 2) * bstep;
            aE  = *(const short8*)a2;
            bE0 = *(const short8*)(b2);
            bE1 = *(const short8*)(b2 + 512);
            bE2 = *(const short8*)(b2 + 1024);
            bE3 = *(const short8*)(b2 + 1536);
        }
        acc[0] = __builtin_amdgcn_mfma_f32_16x16x32_bf16(aO, bO0, acc[0], 0, 0, 0);
        acc[1] = __builtin_amdgcn_mfma_f32_16x16x32_bf16(aO, bO1, acc[1], 0, 0, 0);
        acc[2] = __builtin_amdgcn_mfma_f32_16x16x32_bf16(aO, bO2, acc[2], 0, 0, 0);
        acc[3] = __builtin_amdgcn_mfma_f32_16x16x32_bf16(aO, bO3, acc[3], 0, 0, 0);
        if (kb + 3 < nkb) {
            const unsigned short* a3 = ap + (size_t)(kb + 3) * 32;
            const unsigned short* b3 = bp + (size_t)(kb + 3) * bstep;
            aO  = *(const short8*)a3;
            bO0 = *(const short8*)(b3);
            bO1 = *(const short8*)(b3 + 512);
            bO2 = *(const short8*)(b3 + 1024);
            bO3 = *(const short8*)(b3 + 1536);
        }
    }

    const int r0 = q * 4;
#pragma unroll
    for (int cf = 0; cf < 4; ++cf) {
        int col = n0 + cf * 16 + lr;
        if (col >= N) continue;
        float bv = bias ? bias[col] : 0.f;
#pragma unroll
        for (int r = 0; r < 4; ++r) {
            int row = m0 + 16 * w + r0 + r;
            float v = acc[cf][r] + bv;
            if (act == 1 || (act == 2 && col < 2048)) v = fsigm(v);
            if (caplen) v *= (t < caplen[row] - 1) ? 1.f : 0.f;
            if (C16) C16[(size_t)row * ldc + col] = f2bf(v);
            else     C [(size_t)row * ldc + col] = v;
        }
    }
}

// Standalone GEMM for setup (att_enc), bf16 output
__global__ __launch_bounds__(256) void gemm_setup(
    const unsigned short* __restrict__ A, int lda,
    const unsigned short* __restrict__ Wp, int Npad, int nkb,
    unsigned short* __restrict__ C16, long ldc,
    const float* __restrict__ bias, int N)
{
    gemm_tile(A, lda, Wp, Npad, nkb, nullptr, C16, ldc, bias, N, 0,
              nullptr, 0, blockIdx.x * 64, blockIdx.y * 64);
}

// ---------------------------------------------------------------------------
// Weight packing: Wp[(kb*Npad + n)*32 + kk] = src[k=kb*32+kk][n], bf16.
// mode 0: W1 (K x N1), pad n>=N1 with 0. mode 1: n-concat [W1 | W2].
// ---------------------------------------------------------------------------
__global__ void pack_kernel(const float* __restrict__ W1, const float* __restrict__ W2,
                            int N1, int N2, int Npad, int mode,
                            unsigned short* __restrict__ Wp, int total)
{
    int idx = blockIdx.x * 256 + threadIdx.x;
    if (idx >= total) return;
    int kk = idx & 31;
    int r  = idx >> 5;
    int n  = r % Npad;
    int kb = r / Npad;
    int k  = kb * 32 + kk;
    float v = 0.f;
    if (mode == 0) {
        if (n < N1) v = W1[(size_t)k * N1 + n];
    } else {
        v = (n < N1) ? W1[(size_t)k * N1 + n] : W2[(size_t)k * N2 + (n - N1)];
    }
    Wp[idx] = f2bf(v);
}

__global__ void cast_kernel(const float* __restrict__ src,
                            unsigned short* __restrict__ dst, int n)
{
    int i = (blockIdx.x * 256 + threadIdx.x) * 4;
    if (i >= n) return;
    float4 v = *(const float4*)(src + i);
    dst[i]     = f2bf(v.x);
    dst[i + 1] = f2bf(v.y);
    dst[i + 2] = f2bf(v.z);
    dst[i + 3] = f2bf(v.w);
}

__global__ void bias_prep(const float* __restrict__ bfb, const float* __restrict__ bda,
                          const float* __restrict__ bih, const float* __restrict__ bhh,
                          float* __restrict__ bcat, float* __restrict__ bsum)
{
    int i = blockIdx.x * 256 + threadIdx.x;
    if (i < 2048) { bcat[i] = bfb[i]; bsum[i] = bih[i] + bhh[i]; }
    else if (i < 2560) bcat[i] = bda[i - 2048];
}

__global__ void mean_kernel(const float* __restrict__ enc, float* __restrict__ me)
{
    int d = blockIdx.x * 256 + threadIdx.x;
    int b = blockIdx.y;
    const float* p = enc + (size_t)b * NPIX * ENCD + d;
    float s = 0.0f;
    for (int q = 0; q < NPIX; ++q) s += p[(size_t)q * ENCD];
    me[b * ENCD + d] = s * (1.0f / 196.0f);
}

__global__ void inithc_kernel(const float* __restrict__ me,
                              const float* __restrict__ Wh, const float* __restrict__ bh,
                              const float* __restrict__ Wc, const float* __restrict__ bc,
                              unsigned short* __restrict__ xcat, float* __restrict__ c)
{
    int idx = blockIdx.x * 256 + threadIdx.x;  // 0..32767
    int b = idx >> 9, j = idx & 511;
    const float* m = me + b * ENCD;
    float sh = bh[j], sc = bc[j];
    for (int k = 0; k < ENCD; ++k) {
        float mv = m[k];
        sh += mv * Wh[(size_t)k * DECD + j];
        sc += mv * Wc[(size_t)k * DECD + j];
    }
    xcat[(size_t)b * 3072 + 2560 + j] = f2bf(sh);
    c[idx] = sc;
}

__global__ void copy_misc(const int* __restrict__ caps, const int* __restrict__ lens,
                          float* __restrict__ out)
{
    int i = blockIdx.x * 256 + threadIdx.x;
    if (i < CAPS_SZ) out[PRED_SZ + i] = (float)caps[i];
    else if (i < CAPS_SZ + LENS_SZ) out[PRED_SZ + i] = (float)(lens[i - CAPS_SZ] - 1);
}

// ---------------------------------------------------------------------------
// Persistent decode kernel: all 51 steps, 5 grid barriers per step.
// Phases (bid = blockIdx.x, 256 blocks):
//  S1: bid<40 gadec GEMM | bid 40..196 preds(t-1) GEMM | bid 197..228 h@Whh
//  S2: bid<64 attention softmax (one block per batch row)
//  S3: all 256: awe + gate + xcat build (b=bid>>2, 512-dim chunk=bid&3)
//  S4: bid<128 xcat@Wih k-split GEMM (ntile=bid&31, kslice=bid>>5)
//  S5: bid<128 LSTM reduce + masked h/c update
// ---------------------------------------------------------------------------
__global__ __launch_bounds__(256) void decode_mega(
    const unsigned short* __restrict__ enc16,
    const unsigned short* __restrict__ attenc16,
    const unsigned short* __restrict__ WpG,
    const unsigned short* __restrict__ WpL,
    const unsigned short* __restrict__ WpHH,
    const unsigned short* __restrict__ WpF,
    unsigned short* __restrict__ xcat,
    float* __restrict__ gadec,
    float* __restrict__ gparts,
    float* __restrict__ cst,
    float* __restrict__ alpha,
    const float* __restrict__ bcat,
    const float* __restrict__ bsum,
    const float* __restrict__ Wf,
    const float* __restrict__ bfa,
    const float* __restrict__ bfc,
    const float* __restrict__ emb,
    const int* __restrict__ caps,
    const int* __restrict__ lens,
    float* __restrict__ out,
    unsigned int* __restrict__ barcnt)
{
    const int bid = blockIdx.x;
    const int tid = threadIdx.x;
    __shared__ float smem[2304];
    unsigned int nbar = 0;
    unsigned short* h16 = xcat + 2560;   // lda 3072

    for (int t = 0; t <= TT; ++t) {
        // ---------------- S1 ----------------
        if (bid < 40) {
            gemm_tile(h16, 3072, WpG, 2560, 16, gadec, nullptr, 2560,
                      bcat, 2560, 2, nullptr, 0, bid * 64, 0);
        } else if (bid < 197) {
            if (t > 0)
                gemm_tile(h16, 3072, WpF, NPADFC, 16,
                          out + (size_t)(t - 1) * VOCAB_N, nullptr, (long)TT * VOCAB_N,
                          bfc, VOCAB_N, 0, lens, t - 1, (bid - 40) * 64, 0);
        } else if (bid < 229) {
            gemm_tile(h16, 3072, WpHH, 2048, 16, gparts + 4 * BB * 2048, nullptr, 2048,
                      nullptr, 2048, 0, nullptr, 0, (bid - 197) * 64, 0);
        }
        if (t == TT) break;
        gridbar(barcnt, ++nbar * NBLK);

        // ---------------- S2: attention ----------------
        if (bid < 64) {
            const int b = bid;
            const int lane = tid & 63, wid = tid >> 6;
            float* av = smem;
            float* wv = smem + 512;
            float* es = smem + 1024;
            float* r4 = smem + 1220;
            for (int j = tid; j < 512; j += 256) {
                av[j] = gadec[(size_t)b * 2560 + 2048 + j];
                wv[j] = Wf[j];
            }
            __syncthreads();
            float mya[8], myw[8];
#pragma unroll
            for (int i = 0; i < 8; ++i) {
                mya[i] = av[lane * 8 + i];
                myw[i] = wv[lane * 8 + i];
            }
            for (int p = wid; p < NPIX; p += 4) {
                const unsigned short* ae = attenc16 + ((size_t)(b * NPIX + p)) * 512 + lane * 8;
                short8 e8 = *(const short8*)ae;
                float s = 0.f;
#pragma unroll
                for (int i = 0; i < 8; ++i)
                    s += ftanh(bf2f((unsigned short)e8[i]) + mya[i]) * myw[i];
                for (int off = 32; off; off >>= 1) s += __shfl_down(s, off);
                if (lane == 0) es[p] = s + bfa[0];
            }
            __syncthreads();
            float v = (tid < NPIX) ? es[tid] : -1e30f;
            float m = v;
            for (int off = 32; off; off >>= 1) m = fmaxf(m, __shfl_down(m, off));
            if (lane == 0) r4[wid] = m;
            __syncthreads();
            if (tid == 0) smem[1224] = fmaxf(fmaxf(r4[0], r4[1]), fmaxf(r4[2], r4[3]));
            __syncthreads();
            float ev = (tid < NPIX) ? __expf(v - smem[1224]) : 0.0f;
            float s = ev;
            for (int off = 32; off; off >>= 1) s += __shfl_down(s, off);
            if (lane == 0) r4[wid] = s;
            __syncthreads();
            if (tid == 0) smem[1225] = r4[0] + r4[1] + r4[2] + r4[3];
            __syncthreads();
            if (tid < NPIX) {
                float a = ev / smem[1225];
                alpha[b * NPIX + tid] = a;
                float mk = (t < lens[b] - 1) ? 1.0f : 0.0f;
                out[ALPHAS_OFF + ((size_t)b * TT + t) * NPIX + tid] = a * mk;
            }
        }
        gridbar(barcnt, ++nbar * NBLK);

        // ---------------- S3: awe + gate + xcat ----------------
        {
            const int b = bid >> 2, ch = bid & 3;
            float* as_ = smem;
            float* parr = smem + 256;
            if (tid < NPIX) as_[tid] = alpha[b * NPIX + tid];
            __syncthreads();
            const int psub = tid >> 6, dsub = tid & 63;
            const unsigned short* e = enc16 + ((size_t)b * NPIX + (size_t)psub * 49) * ENCD
                                      + ch * 512 + dsub * 8;
            float s[8];
#pragma unroll
            for (int j = 0; j < 8; ++j) s[j] = 0.f;
            for (int i = 0; i < 49; ++i) {
                short8 v = *(const short8*)(e + (size_t)i * ENCD);
                float a = as_[psub * 49 + i];
#pragma unroll
                for (int j = 0; j < 8; ++j) s[j] += a * bf2f((unsigned short)v[j]);
            }
            float* pp = parr + psub * 512 + dsub * 8;
            *(f32x4*)pp       = (f32x4){s[0], s[1], s[2], s[3]};
            *(f32x4*)(pp + 4) = (f32x4){s[4], s[5], s[6], s[7]};
            __syncthreads();
            const int d = tid * 2;   // 0..510 within chunk
            float2 g = *(const float2*)(gadec + (size_t)b * 2560 + ch * 512 + d);
            float r0 = parr[d]     + parr[512 + d]     + parr[1024 + d]     + parr[1536 + d];
            float r1 = parr[d + 1] + parr[512 + d + 1] + parr[1024 + d + 1] + parr[1536 + d + 1];
            unsigned short* xr = xcat + (size_t)b * 3072 + 512 + ch * 512 + d;
            xr[0] = f2bf(r0 * g.x);
            xr[1] = f2bf(r1 * g.y);
            if (ch == 0) {
                int wword = caps[b * MAXLEN + t];
                for (int j = tid; j < 512; j += 256)
                    xcat[(size_t)b * 3072 + j] = f2bf(emb[(size_t)wword * 512 + j]);
            }
        }
        gridbar(barcnt, ++nbar * NBLK);

        // ---------------- S4: gates xcat GEMM ----------------
        if (bid < 128) {
            const int nt = bid & 31, kz = bid >> 5;
            gemm_tile(xcat + kz * 640, 3072, WpL + (size_t)kz * 20 * 2048 * 32, 2048, 20,
                      gparts + (size_t)kz * BB * 2048, nullptr, 2048,
                      nullptr, 2048, 0, nullptr, 0, nt * 64, 0);
        }
        gridbar(barcnt, ++nbar * NBLK);

        // ---------------- S5: LSTM ----------------
        if (bid < 128) {
            const int idx = bid * 256 + tid;
            const int b = idx >> 9, j = idx & 511;
            float gi = bsum[j], gf = bsum[512 + j];
            float gg = bsum[1024 + j], go = bsum[1536 + j];
#pragma unroll
            for (int sl = 0; sl < 5; ++sl) {
                const float* pg = gparts + (size_t)sl * BB * 2048 + (size_t)b * 2048;
                gi += pg[j]; gf += pg[512 + j]; gg += pg[1024 + j]; go += pg[1536 + j];
            }
            float cn = fsigm(gf) * cst[idx] + fsigm(gi) * ftanh(gg);
            float hn = fsigm(go) * ftanh(cn);
            if (t < lens[b] - 1) {
                cst[idx] = cn;
                xcat[(size_t)b * 3072 + 2560 + j] = f2bf(hn);
            }
        }
        gridbar(barcnt, ++nbar * NBLK);
    }
}

// ---------------------------------------------------------------------------
extern "C" void kernel_launch(void* const* d_in, const int* in_sizes, int n_in,
                              void* d_out, int out_size, void* d_ws, size_t ws_size,
                              hipStream_t stream)
{
    (void)in_sizes; (void)n_in; (void)out_size; (void)ws_size;
    const float* enc        = (const float*)d_in[0];
    const int*   caps       = (const int*)d_in[1];
    const int*   lens       = (const int*)d_in[2];
    const float* emb        = (const float*)d_in[3];
    const float* W_enc_att  = (const float*)d_in[4];
    const float* b_enc_att  = (const float*)d_in[5];
    const float* W_dec_att  = (const float*)d_in[6];
    const float* b_dec_att  = (const float*)d_in[7];
    const float* W_full_att = (const float*)d_in[8];
    const float* b_full_att = (const float*)d_in[9];
    const float* W_init_h   = (const float*)d_in[10];
    const float* b_init_h   = (const float*)d_in[11];
    const float* W_init_c   = (const float*)d_in[12];
    const float* b_init_c   = (const float*)d_in[13];
    const float* W_fbeta    = (const float*)d_in[14];
    const float* b_fbeta    = (const float*)d_in[15];
    const float* W_ih       = (const float*)d_in[16];
    const float* W_hh       = (const float*)d_in[17];
    const float* b_ih       = (const float*)d_in[18];
    const float* b_hh       = (const float*)d_in[19];
    const float* W_fc       = (const float*)d_in[20];
    const float* b_fc       = (const float*)d_in[21];
    float* out = (float*)d_out;

    // ---- workspace carve-up ----
    char* p = (char*)d_ws;
    unsigned short* enc16    = (unsigned short*)p; p += (size_t)BB * NPIX * ENCD * 2;
    unsigned short* attenc16 = (unsigned short*)p; p += (size_t)BB * NPIX * 512 * 2;
    unsigned short* WpG      = (unsigned short*)p; p += (size_t)16 * 2560 * 32 * 2;
    unsigned short* WpL      = (unsigned short*)p; p += (size_t)80 * 2048 * 32 * 2;
    unsigned short* WpHH     = (unsigned short*)p; p += (size_t)16 * 2048 * 32 * 2;
    unsigned short* WpF      = (unsigned short*)p; p += (size_t)16 * NPADFC * 32 * 2;
    unsigned short* WpE      = (unsigned short*)p; p += (size_t)64 * 512 * 32 * 2;
    unsigned short* xcat     = (unsigned short*)p; p += (size_t)BB * 3072 * 2;
    float* gadec  = (float*)p; p += (size_t)BB * 2560 * 4;
    float* gparts = (float*)p; p += (size_t)5 * BB * 2048 * 4;
    float* cst    = (float*)p; p += (size_t)BB * 512 * 4;
    float* alpha  = (float*)p; p += (size_t)BB * NPIX * 4;
    float* me     = (float*)p; p += (size_t)BB * ENCD * 4;
    float* bcat   = (float*)p; p += 2560 * 4;
    float* bsum   = (float*)p; p += 2048 * 4;
    unsigned int* barcnt = (unsigned int*)p; p += 256;

    // ---- setup ----
    hipMemsetAsync((void*)barcnt, 0, 64, stream);
    {
        int n = BB * NPIX * ENCD;
        cast_kernel<<<(n / 4 + 255) / 256, 256, 0, stream>>>(enc, enc16, n);
    }
    { int tot = 16 * 2560 * 32;
      pack_kernel<<<(tot + 255) / 256, 256, 0, stream>>>(W_fbeta, W_dec_att, 2048, 512, 2560, 1, WpG, tot); }
    { int tot = 80 * 2048 * 32;
      pack_kernel<<<(tot + 255) / 256, 256, 0, stream>>>(W_ih, nullptr, 2048, 0, 2048, 0, WpL, tot); }
    { int tot = 16 * 2048 * 32;
      pack_kernel<<<(tot + 255) / 256, 256, 0, stream>>>(W_hh, nullptr, 2048, 0, 2048, 0, WpHH, tot); }
    { int tot = 16 * NPADFC * 32;
      pack_kernel<<<(tot + 255) / 256, 256, 0, stream>>>(W_fc, nullptr, VOCAB_N, 0, NPADFC, 0, WpF, tot); }
    { int tot = 64 * 512 * 32;
      pack_kernel<<<(tot + 255) / 256, 256, 0, stream>>>(W_enc_att, nullptr, 512, 0, 512, 0, WpE, tot); }
    bias_prep<<<10, 256, 0, stream>>>(b_fbeta, b_dec_att, b_ih, b_hh, bcat, bsum);
    mean_kernel<<<dim3(8, 64), 256, 0, stream>>>(enc, me);
    inithc_kernel<<<128, 256, 0, stream>>>(me, W_init_h, b_init_h, W_init_c, b_init_c, xcat, cst);
    gemm_setup<<<dim3(8, 196), 256, 0, stream>>>(enc16, ENCD, WpE, 512, 64,
                                                 attenc16, 512, b_enc_att, 512);
    copy_misc<<<14, 256, 0, stream>>>(caps, lens, out);

    // ---- persistent decode ----
    decode_mega<<<NBLK, 256, 0, stream>>>(
        enc16, attenc16, WpG, WpL, WpHH, WpF,
        xcat, gadec, gparts, cst, alpha,
        bcat, bsum, W_full_att, b_full_att, b_fc,
        emb, caps, lens, out, barcnt);
}